// Round 12
// baseline (84.317 us; speedup 1.0000x reference)
//
#include <hip/hip_runtime.h>
#include <math.h>

constexpr int BN = 8192;
constexpr int MN = 6;

// E = -T*log2(e)*d2 with T=2:  E = 2TL*g - TL*sq_i - TL*sq_j,  L=log2(e)
constexpr float TL    = 2.8853900817779268f;   // 2*log2(e)
constexpr float SCL_Z = 2.4022448795936154f;   // sqrt(2*T*L)

typedef __bf16 bf16_t;
typedef bf16_t bf16x8 __attribute__((ext_vector_type(8)));
typedef float f32x4 __attribute__((ext_vector_type(4)));

union PK { bf16_t h[8]; uint4 u; };

__device__ __forceinline__ bf16x8 frag_of(uint4 u) {
    return __builtin_bit_cast(bf16x8, u);
}

__device__ __host__ __forceinline__ int midx(int a, int b) {
    return 8 * a - (a * (a - 1)) / 2 + (b - a);   // upper-tri 8x8 packed
}

// Combined fragment store C: per 16-row tile, 4 octets of 16 uint4 (1024 B):
//   s0=zh  s1=zl  s2=a3  s3=b3
// A-frag octet perm {zh,zl,zh,a3} -> pa(g) = (g==3)?2:(g&1)
// B-frag octet perm {zh,zh,zl,b3} -> pb(g) = (g==3)?3:(g>>1)

// ---------------------------------------------------------------------------
// K0: blocks 0..191 -> pack fragments; 192..223 -> angle second moments.
// ---------------------------------------------------------------------------
__global__ __launch_bounds__(256) void prep_ang(const float* __restrict__ x,
                                                const float* __restrict__ ang,
                                                uint4* __restrict__ C,
                                                float* __restrict__ angp) {
    const int blk = blockIdx.x;
    const int tid = threadIdx.x;
    if (blk < 192) {
        int idx = blk * 256 + tid;
        int n = idx >> 13;
        int j = idx & (BN - 1);
        const float* p = x + (size_t)j * 48 + n * 8;

        PK zh, zl, a3, b3;
        float sq = 0.f;
#pragma unroll
        for (int k = 0; k < 8; ++k) {
            float v = p[k];
            sq = fmaf(v, v, sq);
            float z = SCL_Z * v;
            bf16_t h = (bf16_t)z;
            zh.h[k] = h;
            zl.h[k] = (bf16_t)(z - (float)h);
        }
        float s = -TL * sq;
        bf16_t sh = (bf16_t)s;
        bf16_t sl = (bf16_t)(s - (float)sh);
        bf16_t one = (bf16_t)1.0f, zero = (bf16_t)0.0f;
        a3.h[0] = one; a3.h[1] = one; a3.h[2] = sh;  a3.h[3] = sl;
        b3.h[0] = sh;  b3.h[1] = sl;  b3.h[2] = one; b3.h[3] = one;
#pragma unroll
        for (int k = 4; k < 8; ++k) { a3.h[k] = zero; b3.h[k] = zero; }

        size_t base = ((size_t)(n * 512 + (j >> 4))) * 64 + (j & 15);
        C[base +  0] = zh.u;
        C[base + 16] = zl.u;
        C[base + 32] = a3.u;
        C[base + 48] = b3.u;
    } else {
        const int i = (blk - 192) * 256 + tid;
        float v[8];
#pragma unroll
        for (int k = 0; k < 4; ++k) __sincosf(ang[i * 4 + k], &v[k], &v[4 + k]);
        float acc[44];
        int c = 0;
#pragma unroll
        for (int a = 0; a < 8; ++a)
#pragma unroll
            for (int bq = a; bq < 8; ++bq) acc[c++] = v[a] * v[bq];
#pragma unroll
        for (int a = 0; a < 8; ++a) acc[36 + a] = v[a];

#pragma unroll
        for (int q = 0; q < 44; ++q) {
            float s = acc[q];
            s += __shfl_xor(s, 1);  s += __shfl_xor(s, 2);
            s += __shfl_xor(s, 4);  s += __shfl_xor(s, 8);
            s += __shfl_xor(s, 16); s += __shfl_xor(s, 32);
            acc[q] = s;
        }
        __shared__ float sm[4][44];
        const int w = tid >> 6, lane = tid & 63;
        if (lane == 0)
#pragma unroll
            for (int q = 0; q < 44; ++q) sm[w][q] = acc[q];
        __syncthreads();
        if (tid < 44)
            angp[(blk - 192) * 44 + tid] =
                sm[0][tid] + sm[1][tid] + sm[2][tid] + sm[3][tid];
    }
}

// ---------------------------------------------------------------------------
// K1: symmetric sweep — verbatim R8 kernel (42.9 us, no spill).
// Block = (mode m, strip-pair sp, parity h); 768 blocks x 512 thr.
// Strip s in {sp, 127-sp}: row tiles 4s..4s+3; wave w sweeps col tiles
// jt >= 4s+4 with jt == 2w+h (mod 16).  Each tile credited twice:
// colsum -> racc, rowsum -> LDS cred[jt][16], residue-partitioned across
// waves (race-free, no atomics).  Diagonal wedge handled in K2.
// ---------------------------------------------------------------------------
__global__ __launch_bounds__(512, 6) void pair_sweep(const uint4* __restrict__ C,
                                                     float* __restrict__ colsumP,
                                                     unsigned short* __restrict__ credP) {
    const int tid  = threadIdx.x;
    const int lane = tid & 63;
    const int w    = __builtin_amdgcn_readfirstlane(tid >> 6);
    const int b    = blockIdx.x;
    const int m    = b >> 7;
    const int sp   = (b >> 1) & 63;
    const int h    = b & 1;
    const int rho  = 2 * w + h;

    __shared__ float cred[8192];       // [512 col-tiles][16 cols]
    __shared__ float smem[2][8][64];
    for (int q = tid; q < 8192; q += 512) cred[q] = 0.f;
    __syncthreads();

    const int g  = lane >> 4;
    const int pa = (g == 3) ? 2 : (g & 1);
    const int pb = (g == 3) ? 3 : (g >> 1);
    const int cl = lane & 15;
    const f32x4 z4 = {0.f, 0.f, 0.f, 0.f};
    const uint4* mbase = C + (size_t)m * 512 * 64;
    const uint4* bcol  = mbase + pb * 16 + cl;

#pragma unroll 1
    for (int sidx = 0; sidx < 2; ++sidx) {
        const int s = sidx ? (127 - sp) : sp;

        bf16x8 af[4];
#pragma unroll
        for (int t = 0; t < 4; ++t)
            af[t] = frag_of(mbase[(size_t)(4 * s + t) * 64 + pa * 16 + cl]);

        float racc[16];
#pragma unroll
        for (int q = 0; q < 16; ++q) racc[q] = 0.f;

        const int start = 4 * s + 4;
        const int first = start + (int)(((unsigned)(rho - start)) & 15u);
        const int f0 = (first < 512) ? first : 0;   // safe addr even if empty

        uint4 b0 = bcol[(size_t)f0 * 64];
        uint4 b1 = bcol[(size_t)(f0 + 16) * 64];
        for (int jt = first; jt < 512; jt += 16) {
            uint4 p0 = bcol[(size_t)(jt + 32) * 64];   // over-read stays in ws
            bf16x8 bf = frag_of(b0);
            float rsum = 0.f;
#pragma unroll
            for (int t = 0; t < 4; ++t) {
                f32x4 d = __builtin_amdgcn_mfma_f32_16x16x32_bf16(af[t], bf, z4, 0, 0, 0);
#pragma unroll
                for (int r = 0; r < 4; ++r) {
                    float e = __builtin_amdgcn_exp2f(d[r]);
                    racc[t * 4 + r] += e;
                    rsum += e;
                }
            }
            rsum += __shfl_xor(rsum, 16);
            rsum += __shfl_xor(rsum, 32);
            if (lane < 16) cred[jt * 16 + lane] += rsum;
            b0 = b1; b1 = p0;
        }

        // colsum: reduce over the 16 column lanes
#pragma unroll
        for (int q = 0; q < 16; ++q) {
            float v = racc[q];
            v += __shfl_xor(v, 1);
            v += __shfl_xor(v, 2);
            v += __shfl_xor(v, 4);
            v += __shfl_xor(v, 8);
            racc[q] = v;
        }
        if (cl == 0) {
#pragma unroll
            for (int t = 0; t < 4; ++t)
#pragma unroll
                for (int r = 0; r < 4; ++r)
                    smem[sidx][w][t * 16 + g * 4 + r] = racc[t * 4 + r];
        }
    }

    __syncthreads();

    if (tid < 128) {
        const int si = tid >> 6, row = tid & 63;
        float ssum = 0.f;
#pragma unroll
        for (int ww = 0; ww < 8; ++ww) ssum += smem[si][ww][row];
        const int s = si ? (127 - sp) : sp;
        colsumP[(size_t)h * (MN * BN) + m * BN + s * 64 + row] = ssum;
    }

    // flush parity-h credit rows as bf16 contributor slot
    for (int q = tid; q < 4096; q += 512) {
        const int jt = 2 * (q >> 4) + h, c = q & 15;
        bf16_t v = (bf16_t)cred[jt * 16 + c];
        credP[((size_t)((m * 64 + sp) * 2 + h)) * 4096 + q] =
            __builtin_bit_cast(unsigned short, v);
    }
}

// ---------------------------------------------------------------------------
// K2: fused wedge + log reduction + (last block) final assembly.
// 96 blocks x 512.  Wave w computes the diagonal 4x4 wedge for strip
// s = (b&15)*8 + w of mode m = b>>4 (reads C — ready; self-pairs skipped).
// Then each thread owns one row: total = 2 colsum halves + wedge +
// 64 bf16 credit slots; log; block partial -> lp[b]; last-done block
// (threadfence + device atomicAdd) assembles the 9 outputs.
// ---------------------------------------------------------------------------
__global__ __launch_bounds__(512) void log_wedge_final(
        const uint4* __restrict__ C,
        const float* __restrict__ colsumP,
        const unsigned short* __restrict__ credP,
        const float* __restrict__ angp,
        float* __restrict__ lp,
        int* __restrict__ cnt,
        float* __restrict__ out) {
    const int tid  = threadIdx.x;
    const int b    = blockIdx.x;     // 0..95
    const int m    = b >> 4;
    const int lane = tid & 63;
    const int w    = tid >> 6;

    __shared__ float smW[8][64];
    __shared__ float smR[8];
    __shared__ int   isLast;

    // ---- Phase W: diagonal 4x4 wedge for strip s (self-pairs skipped) ----
    {
        const int s  = (b & 15) * 8 + w;
        const int g  = lane >> 4;
        const int pa = (g == 3) ? 2 : (g & 1);
        const int pb = (g == 3) ? 3 : (g >> 1);
        const int cl = lane & 15;
        const int dd = cl - 4 * g;
        const f32x4 z4 = {0.f, 0.f, 0.f, 0.f};
        const uint4* mbase = C + (size_t)m * 512 * 64;

        bf16x8 af[4];
#pragma unroll
        for (int t = 0; t < 4; ++t)
            af[t] = frag_of(mbase[(size_t)(4 * s + t) * 64 + pa * 16 + cl]);

        float racc[16];
#pragma unroll
        for (int q = 0; q < 16; ++q) racc[q] = 0.f;

#pragma unroll
        for (int u = 0; u < 4; ++u) {
            bf16x8 bf = frag_of(mbase[(size_t)(4 * s + u) * 64 + pb * 16 + cl]);
#pragma unroll
            for (int t = 0; t < 4; ++t) {
                f32x4 d = __builtin_amdgcn_mfma_f32_16x16x32_bf16(af[t], bf, z4, 0, 0, 0);
#pragma unroll
                for (int r = 0; r < 4; ++r) {
                    float e = __builtin_amdgcn_exp2f(d[r]);
                    if (u == t && dd == r) e = 0.f;
                    racc[t * 4 + r] += e;
                }
            }
        }
#pragma unroll
        for (int q = 0; q < 16; ++q) {
            float v = racc[q];
            v += __shfl_xor(v, 1);
            v += __shfl_xor(v, 2);
            v += __shfl_xor(v, 4);
            v += __shfl_xor(v, 8);
            racc[q] = v;
        }
        if (cl == 0) {
#pragma unroll
            for (int t = 0; t < 4; ++t)
#pragma unroll
                for (int r = 0; r < 4; ++r)
                    smW[w][t * 16 + g * 4 + r] = racc[t * 4 + r];
        }
    }
    __syncthreads();

    // ---- Phase L: per-row total, log, block reduce ----
    const int idx = b * 512 + tid;
    const int i   = idx & (BN - 1);
    const int jt  = i >> 4, c = i & 15;
    const int hh  = jt & 1;
    const int q   = (jt >> 1) * 16 + c;

    float v = colsumP[idx] + colsumP[MN * BN + idx] + smW[w][lane];
    const unsigned short* basep = credP + ((size_t)(m * 128 + hh)) * 4096 + q;
#pragma unroll 8
    for (int sp = 0; sp < 64; ++sp) {
        unsigned short u = basep[(size_t)sp * 8192];
        v += (float)__builtin_bit_cast(bf16_t, u);
    }
    float lg = logf(v);
    lg += __shfl_xor(lg, 1);
    lg += __shfl_xor(lg, 2);
    lg += __shfl_xor(lg, 4);
    lg += __shfl_xor(lg, 8);
    lg += __shfl_xor(lg, 16);
    lg += __shfl_xor(lg, 32);
    if (lane == 0) smR[w] = lg;
    __syncthreads();

    if (tid == 0) {
        float s = 0.f;
#pragma unroll
        for (int k = 0; k < 8; ++k) s += smR[k];
        lp[b] = s;
        __threadfence();                       // release lp[b]
        int prev = atomicAdd(cnt, 1);          // device scope
        isLast = (prev == 95) ? 1 : 0;
    }
    __syncthreads();

    // ---- Phase F: last-done block assembles the outputs ----
    if (isLast && tid == 0) {
        __threadfence();                       // acquire all lp[]
        const volatile float* vlp = lp;

        float mom[44];
#pragma unroll
        for (int k = 0; k < 44; ++k) mom[k] = 0.f;
        for (int bk = 0; bk < 32; ++bk)
#pragma unroll
            for (int k = 0; k < 44; ++k) mom[k] += angp[bk * 44 + k];

        float sm[4], cm[4];
#pragma unroll
        for (int k = 0; k < 4; ++k) {
            float S = mom[36 + k], Cc = mom[40 + k];
            float hyp = sqrtf(S * S + Cc * Cc);
            sm[k] = S / hyp;
            cm[k] = Cc / hyp;
        }
        auto COV = [&](int k, int l) -> float {
            int ks = k < l ? k : l, kl = k < l ? l : k;
            float mss = mom[midx(ks, kl)];
            float msc_kl = mom[midx(k, l + 4)];
            float msc_lk = mom[midx(l, k + 4)];
            float mcc = mom[midx(ks + 4, kl + 4)];
            return (cm[k] * cm[l] * mss - cm[k] * sm[l] * msc_kl -
                    sm[k] * cm[l] * msc_lk + sm[k] * sm[l] * mcc) *
                   (1.0f / (float)BN);
        };
        float var[4] = {COV(0, 0), COV(1, 1), COV(2, 2), COV(3, 3)};
        float spread = 0.f;
        const int pk[6] = {0, 0, 0, 1, 1, 2};
        const int pl[6] = {1, 2, 3, 2, 3, 3};
#pragma unroll
        for (int p = 0; p < 6; ++p) {
            float cv = COV(pk[p], pl[p]);
            float den = sqrtf(var[pk[p]] * var[pl[p]] + 1e-8f);
            float cr = cv / den;
            spread += cr * cr;
        }
        spread *= (1.0f / 6.0f);

        const float wgt[6] = {0.0f, 0.19615242270663188f, 0.4641016151377544f,
                              0.7320508075688773f, 0.9282032302755088f, 1.0f};
        const float logBm1 = logf((float)(BN - 1));
        float total_unif = 0.f, unif[6];
#pragma unroll
        for (int mm = 0; mm < 6; ++mm) {
            float s = 0.f;
            for (int k = 0; k < 16; ++k) s += vlp[mm * 16 + k];
            unif[mm] = s * (1.0f / (float)BN) - logBm1;
            total_unif += wgt[mm] * unif[mm];
        }
        out[0] = total_unif;
        out[1] = spread;
        out[2] = total_unif + spread;
#pragma unroll
        for (int mm = 0; mm < 6; ++mm) out[3 + mm] = unif[mm];
    }
}

extern "C" void kernel_launch(void* const* d_in, const int* in_sizes, int n_in,
                              void* d_out, int out_size, void* d_ws, size_t ws_size,
                              hipStream_t stream) {
    const float* angles  = (const float*)d_in[0];   // (8192, 4) f32
    const float* fourier = (const float*)d_in[1];   // (8192, 48) f32
    float* out = (float*)d_out;                     // 9 floats

    char* ws = (char*)d_ws;
    uint4* C              = (uint4*)(ws + 0);                 // 3,145,728 B
    unsigned short* credP = (unsigned short*)(ws + 3145728);  // 6,291,456 B
    float* colsumP        = (float*)(ws + 9437184);           // 393,216 B
    float* lp             = (float*)(ws + 9830400);           // 384 B
    float* angp           = (float*)(ws + 9830784);           // 5,632 B
    int*   cnt            = (int*)(ws + 9836416);             // 4 B

    hipMemsetAsync(cnt, 0, sizeof(int), stream);
    prep_ang<<<dim3(224), dim3(256), 0, stream>>>(fourier, angles, C, angp);
    pair_sweep<<<dim3(768), dim3(512), 0, stream>>>(C, colsumP, credP);
    log_wedge_final<<<dim3(96), dim3(512), 0, stream>>>(C, colsumP, credP,
                                                        angp, lp, cnt, out);
}